// Round 3
// baseline (632.692 us; speedup 1.0000x reference)
//
#include <hip/hip_runtime.h>
#include <cstdint>

#define NROWS_HALF 32768
#define NPTS 1000
#define QC_OFF 4194304            // quantized_coord offset in d_out (floats)
#define LOSS_OFF 8388608          // loss offset in d_out (floats)

// ws layout in ushort units (bf16 stored as raw ushort):
//   [0,64512)        Vh_nd [1008][64]   (RN hi; rows 1000..1007 zero)
//   [64512,129024)   Vl_nd [1008][64]   (RN lo residual)
//   [129024,194560)  VhT   [64][1024]   (RN hi; cols 1000..1023 zero)
//   byte 520192: fp32 loss accumulator
#define U_VH_ND 0
#define U_VL_ND 64512
#define U_VHT   129024
#define WS_LOSS_BYTE 520192

#define XC_STRIDE 1044            // fp32 words per row slab; 1044%32==20
#define X_STRIDE 68
#define MT_STRIDE 33

typedef short short8 __attribute__((ext_vector_type(8)));
typedef float float4v __attribute__((ext_vector_type(4)));

#define MFMA16(a, b, c) __builtin_amdgcn_mfma_f32_16x16x32_bf16((a), (b), (c), 0, 0, 0)

// ---------------- Threefry-2x32 (20 rounds), matches JAX ----------------
__host__ __device__ __forceinline__ void tf2x32(uint32_t k0, uint32_t k1,
                                                uint32_t x0, uint32_t x1,
                                                uint32_t& o0, uint32_t& o1) {
  const uint32_t k2 = k0 ^ k1 ^ 0x1BD11BDAu;
#define TF_R(r) { x0 += x1; x1 = (x1 << (r)) | (x1 >> (32 - (r))); x1 ^= x0; }
  x0 += k0; x1 += k1;
  TF_R(13) TF_R(15) TF_R(26) TF_R(6)
  x0 += k1; x1 += k2 + 1u;
  TF_R(17) TF_R(29) TF_R(16) TF_R(24)
  x0 += k2; x1 += k0 + 2u;
  TF_R(13) TF_R(15) TF_R(26) TF_R(6)
  x0 += k0; x1 += k1 + 3u;
  TF_R(17) TF_R(29) TF_R(16) TF_R(24)
  x0 += k1; x1 += k2 + 4u;
  TF_R(13) TF_R(15) TF_R(26) TF_R(6)
  x0 += k2; x1 += k0 + 5u;
#undef TF_R
  o0 = x0; o1 = x1;
}

// gumbel(bits) = -log(-log(u + 1e-20) + 1e-20), u = (bits>>9 | 1.0f) - 1.0f
__device__ __forceinline__ float gumbel_from_bits(uint32_t bits) {
  const uint32_t mant = bits >> 9;
  const float u = __uint_as_float(mant | 0x3f800000u) - 1.0f;
  const float delta = (float)(8388608u - mant) * 1.1920928955078125e-7f;
  float l;
  if (delta < 0.00390625f) {
    l = -(delta + 0.5f * delta * delta + 0.33333333f * delta * delta * delta);
  } else {
    l = __logf(u + 1e-20f);
  }
  return -__logf(-l + 1e-20f);
}

// round-to-nearest-even bf16 (returns 16-bit pattern in low bits)
__device__ __forceinline__ uint32_t rn16(float f) {
  uint32_t u = __float_as_uint(f);
  return (u + 0x7FFFu + ((u >> 16) & 1u)) >> 16;
}

// split fp32 pair -> packed RN bf16 hi pair + RN bf16 lo (residual) pair
__device__ __forceinline__ void split2_rn(float f0, float f1, uint32_t& hi, uint32_t& lo) {
  uint32_t h0 = rn16(f0), h1 = rn16(f1);
  hi = h0 | (h1 << 16);
  float l0 = f0 - __uint_as_float(h0 << 16);
  float l1 = f1 - __uint_as_float(h1 << 16);
  lo = rn16(l0) | (rn16(l1) << 16);
}

__device__ __forceinline__ void split8_rn(const float* p, short8& hi, short8& lo) {
  float4 f0 = *(const float4*)p;
  float4 f1 = *(const float4*)(p + 4);
  union { uint32_t u[4]; short8 s; } H, L;
  split2_rn(f0.x, f0.y, H.u[0], L.u[0]);
  split2_rn(f0.z, f0.w, H.u[1], L.u[1]);
  split2_rn(f1.x, f1.y, H.u[2], L.u[2]);
  split2_rn(f1.z, f1.w, H.u[3], L.u[3]);
  hi = H.s; lo = L.s;
}

__device__ __forceinline__ short8 as_s8(uint4 v) {
  union { uint4 u; short8 s; } c; c.u = v; return c.s;
}

__device__ __forceinline__ float grid_vec(int n, int c, const float* __restrict__ lw,
                                          const float* __restrict__ lb) {
  int jx = (n / 10) % 10, iy = n / 100, kz = n % 10;
  const double step = 1.5 / 9.0;
  float gx = (float)(jx * step), gy = (float)(iy * step), gz = (float)(kz * step);
  return gx * lw[c * 3 + 0] + gy * lw[c * 3 + 1] + gz * lw[c * 3 + 2] + lb[c];
}

// ---------------- setup: RN bf16 split V in both layouts, loss=0 ----------------
__global__ void setup_kernel(const float* __restrict__ lw, const float* __restrict__ lb,
                             ushort* __restrict__ wsu) {
  int idx = blockIdx.x * 256 + threadIdx.x;
  if (idx < 64512) {
    int n = idx >> 6, c = idx & 63;
    float v = (n < NPTS) ? grid_vec(n, c, lw, lb) : 0.f;
    uint32_t h = rn16(v);
    float fl = v - __uint_as_float(h << 16);
    wsu[U_VH_ND + idx] = (ushort)h;
    wsu[U_VL_ND + idx] = (ushort)rn16(fl);
  } else if (idx < 130048) {
    int i2 = idx - 64512;              // d*1024 + n
    int d = i2 >> 10, n = i2 & 1023;
    float v = (n < NPTS) ? grid_vec(n, d, lw, lb) : 0.f;
    wsu[U_VHT + i2] = (ushort)rn16(v);
  } else if (idx == 130048) {
    *(float*)((char*)wsu + WS_LOSS_BYTE) = 0.f;
  }
}

// ---------------- fused main kernel: 8192 blocks x 256 ----------------
// Block handles 8 local rows: lr 0..3 -> g0+lr, lr 4..7 -> g0+lr-4+32768 (threefry pairs)
__global__ __launch_bounds__(256, 4) void fused_kernel(
    const float* __restrict__ inp, const float* __restrict__ emb,
    const float* __restrict__ lws, const ushort* __restrict__ wsu,
    float* __restrict__ out, float* __restrict__ loss_acc,
    uint32_t kc0, uint32_t kc1, uint32_t kp0, uint32_t kp1) {

  __shared__ float xc_s[8 * XC_STRIDE];   // logits (fp32) -> packed bf16 weights -> MT
  __shared__ float x_s[8 * X_STRIDE];     // input rows; later q output
  __shared__ float xp_s[8 * 32];          // codebook logits
  __shared__ float invW_s[8];
  __shared__ float kl_s;

  const int t = threadIdx.x;
  const int lane = t & 63;
  const int w = t >> 6;
  const int quad = lane >> 4;
  const int mn = lane & 15;
  const int g0 = blockIdx.x * 4;

  if (t == 0) kl_s = 0.f;

  // ---- load 8 input rows ----
  #pragma unroll
  for (int it = 0; it < 2; ++it) {
    int idx = it * 256 + t;
    int rl = idx >> 6, d = idx & 63;
    int row = (rl < 4) ? (g0 + rl) : (g0 + rl - 4 + NROWS_HALF);
    x_s[rl * X_STRIDE + d] = inp[row * 64 + d];
  }
  __syncthreads();

  // ---- GEMM1 (MFMA): logits[8][1008] = X[8][64] . Vt, split RN-bf16 (hi+lo) ----
  {
    short8 ah[2], al[2];
    #pragma unroll
    for (int s = 0; s < 2; ++s)
      split8_rn(&x_s[(mn & 7) * X_STRIDE + s * 32 + quad * 8], ah[s], al[s]);
    const ushort* Vh = wsu + U_VH_ND;
    const ushort* Vl = wsu + U_VL_ND;
    for (int j = w; j < 63; j += 4) {
      const int nb = (j * 16 + mn) * 64 + quad * 8;
      uint4 bh0 = *(const uint4*)(Vh + nb);
      uint4 bl0 = *(const uint4*)(Vl + nb);
      uint4 bh1 = *(const uint4*)(Vh + nb + 32);
      uint4 bl1 = *(const uint4*)(Vl + nb + 32);
      float4v acc = {0.f, 0.f, 0.f, 0.f};
      acc = MFMA16(ah[0], as_s8(bh0), acc);
      acc = MFMA16(ah[0], as_s8(bl0), acc);
      acc = MFMA16(al[0], as_s8(bh0), acc);
      acc = MFMA16(ah[1], as_s8(bh1), acc);
      acc = MFMA16(ah[1], as_s8(bl1), acc);
      acc = MFMA16(al[1], as_s8(bh1), acc);
      if (quad < 2) {   // rows 8..15 of C are duplicates; store m = quad*4+r < 8
        #pragma unroll
        for (int r = 0; r < 4; ++r)
          xc_s[(quad * 4 + r) * XC_STRIDE + j * 16 + mn] = acc[r];
      }
    }
  }
  __syncthreads();

  // ---- fused phase 3+4 (wave-local: rows rA=w, rB=w+4; threefry pair) ----
  {
    const int rA = w, rB = w + 4;
    const uint32_t rowAg = (uint32_t)(g0 + w);
    float* rpA = &xc_s[rA * XC_STRIDE];
    float* rpB = &xc_s[rB * XC_STRIDE];
    float la[16], lb[16];
    #pragma unroll
    for (int i = 0; i < 16; ++i) {
      int n = lane + 64 * i;
      bool v = n < NPTS;
      la[i] = v ? rpA[n] : -1e30f;
      lb[i] = v ? rpB[n] : -1e30f;
    }
    float mA = la[0], mB = lb[0];
    #pragma unroll
    for (int i = 1; i < 16; ++i) { mA = fmaxf(mA, la[i]); mB = fmaxf(mB, lb[i]); }
    #pragma unroll
    for (int off = 32; off > 0; off >>= 1) {
      mA = fmaxf(mA, __shfl_xor(mA, off));
      mB = fmaxf(mB, __shfl_xor(mB, off));
    }
    // KL stats (exp(la - m); sentinel -1e30 -> exp==0, 0*(-1e30)== -0 ok)
    float s0A = 0.f, s1A = 0.f, s0B = 0.f, s1B = 0.f;
    #pragma unroll
    for (int i = 0; i < 16; ++i) {
      float eA = __expf(la[i] - mA); s0A += eA; s1A += eA * la[i];
      float eB = __expf(lb[i] - mB); s0B += eB; s1B += eB * lb[i];
    }
    #pragma unroll
    for (int off = 32; off > 0; off >>= 1) {
      s0A += __shfl_xor(s0A, off); s1A += __shfl_xor(s1A, off);
      s0B += __shfl_xor(s0B, off); s1B += __shfl_xor(s1B, off);
    }
    if (lane == 0) {
      atomicAdd(&kl_s, (s1A / s0A - (mA + __logf(s0A)) + 6.9077552790f)
                     + (s1B / s0B - (mB + __logf(s0B)) + 6.9077552790f));
    }
    // gumbel-softmax single pass: w = exp((logit+g)/2 - m/2), RN-bf16, in-place packed
    const float mA2 = mA * 0.5f, mB2 = mB * 0.5f;
    uint32_t* wuA = (uint32_t*)rpA;
    uint32_t* wuB = (uint32_t*)rpB;
    const uint32_t swzA = ((uint32_t)rA & 3u) * 8u;
    const uint32_t swzB = ((uint32_t)rB & 3u) * 8u;
    float sA = 0.f, sB = 0.f;
    #pragma unroll
    for (int i = 0; i < 16; ++i) {
      uint32_t n = (uint32_t)(lane + 64 * i);
      uint32_t j0 = rowAg * 1000u + n;
      uint32_t y0, y1;
      tf2x32(kc0, kc1, j0, j0 + 32768000u, y0, y1);
      float tA = (la[i] + gumbel_from_bits(y0)) * 0.5f - mA2;
      float tB = (lb[i] + gumbel_from_bits(y1)) * 0.5f - mB2;
      uint32_t hA = rn16(__expf(tA));   // sentinel rows -> exp==0 -> weight 0
      uint32_t hB = rn16(__expf(tB));
      sA += __uint_as_float(hA << 16);  // sum of truncated weights (matches GEMM2 A)
      sB += __uint_as_float(hB << 16);
      uint32_t pA = (uint32_t)__shfl_xor((int)hA, 1);
      uint32_t pB = (uint32_t)__shfl_xor((int)hB, 1);
      if (!(lane & 1)) {                // even lane packs (n, n+1)
        wuA[(n ^ swzA) >> 1] = hA | (pA << 16);
        wuB[(n ^ swzB) >> 1] = hB | (pB << 16);
      }
    }
    #pragma unroll
    for (int off = 32; off > 0; off >>= 1) { sA += __shfl_xor(sA, off); sB += __shfl_xor(sB, off); }
    if (lane == 0) { invW_s[rA] = 1.f / sA; invW_s[rB] = 1.f / sB; }
  }
  __syncthreads();

  // ---- GEMM2 (MFMA): qc[8][64] = W_bf16[8][1024] . VhT; wave w -> d-tile w ----
  {
    const ushort* VhT = wsu + U_VHT;
    const int dq = w * 16 + mn;                 // output d column
    const int arow = mn & 7;                    // dup rows 8..15
    const uint32_t* wrow = (const uint32_t*)&xc_s[arow * XC_STRIDE];
    const uint32_t swz = ((uint32_t)arow & 3u) * 8u;
    float4v acc = {0.f, 0.f, 0.f, 0.f};
    for (int s = 0; s < 32; ++s) {
      uint32_t n0 = (uint32_t)(s * 32 + quad * 8);
      uint4 aw = *(const uint4*)(wrow + ((n0 ^ swz) >> 1));
      uint4 bh = *(const uint4*)(VhT + dq * 1024 + n0);
      acc = MFMA16(as_s8(aw), as_s8(bh), acc);
    }
    if (quad < 2) {
      #pragma unroll
      for (int r = 0; r < 4; ++r) {
        int m = quad * 4 + r;                   // 0..7
        int grow = (m < 4) ? (g0 + m) : (g0 + m - 4 + NROWS_HALF);
        out[QC_OFF + grow * 64 + dq] = acc[r] * invW_s[m];
      }
    }
  }
  __syncthreads();   // xc free -> alias MT

  // ---- MT[64][33] (d-major): MT[d][m] = sum_e embK[k,n,e]*lin_ws[k,e,d] ----
  float* MT = xc_s;
  #pragma unroll
  for (int e = 0; e < 8; ++e) {
    int idx = e * 256 + t;     // 2048 entries: mm = idx>>6, d = idx&63
    int mm = idx >> 6, d = idx & 63, k = mm >> 3;
    float a = 0.f;
    #pragma unroll
    for (int ee = 0; ee < 16; ++ee) a += emb[mm * 16 + ee] * lws[(k * 16 + ee) * 64 + d];
    MT[d * MT_STRIDE + mm] = a;
  }
  __syncthreads();

  // ---- phase 5a: xp = x . M^T (thread: row t>>5, m32 = t&31) ----
  {
    const int rl = t >> 5, m32 = t & 31;
    float a = 0.f;
    #pragma unroll
    for (int d = 0; d < 64; ++d)
      a = fmaf(x_s[rl * X_STRIDE + d], MT[d * MT_STRIDE + m32], a);
    xp_s[rl * 32 + m32] = a;
  }
  __syncthreads();

  // ---- phase 5b: per (pair p, k): KL_p, gumbel-softmax, q = ip . embK ----
  float* q_s = x_s;   // x dead after 5a
  if (t < 16) {
    const int p = t >> 2, k = t & 3;
    const int rA = p, rB = p + 4;
    float xpA[8], xpB[8];
    #pragma unroll
    for (int n = 0; n < 8; ++n) {
      xpA[n] = xp_s[rA * 32 + k * 8 + n];
      xpB[n] = xp_s[rB * 32 + k * 8 + n];
    }
    float mA = xpA[0], mB = xpB[0];
    #pragma unroll
    for (int n = 1; n < 8; ++n) { mA = fmaxf(mA, xpA[n]); mB = fmaxf(mB, xpB[n]); }
    float s0A = 0.f, s1A = 0.f, s0B = 0.f, s1B = 0.f;
    #pragma unroll
    for (int n = 0; n < 8; ++n) {
      float eA = __expf(xpA[n] - mA); s0A += eA; s1A += eA * xpA[n];
      float eB = __expf(xpB[n] - mB); s0B += eB; s1B += eB * xpB[n];
    }
    atomicAdd(&kl_s, (s1A / s0A - (mA + __logf(s0A)) + 2.0794415417f) +
                     (s1B / s0B - (mB + __logf(s0B)) + 2.0794415417f));
    uint32_t base = (uint32_t)(g0 + p) * 32u + (uint32_t)k * 8u;
    float tA[8], tB[8], m2A = -3.0e38f, m2B = -3.0e38f;
    #pragma unroll
    for (int n = 0; n < 8; ++n) {
      uint32_t y0, y1;
      tf2x32(kp0, kp1, base + n, base + n + 1048576u, y0, y1);
      tA[n] = (xpA[n] + gumbel_from_bits(y0)) * 0.5f;
      tB[n] = (xpB[n] + gumbel_from_bits(y1)) * 0.5f;
      m2A = fmaxf(m2A, tA[n]); m2B = fmaxf(m2B, tB[n]);
    }
    float wvA[8], wvB[8], swA = 0.f, swB = 0.f;
    #pragma unroll
    for (int n = 0; n < 8; ++n) {
      wvA[n] = __expf(tA[n] - m2A); swA += wvA[n];
      wvB[n] = __expf(tB[n] - m2B); swB += wvB[n];
    }
    float invA = 1.0f / swA, invB = 1.0f / swB;
    #pragma unroll
    for (int e = 0; e < 16; ++e) {
      float aA = 0.f, aB = 0.f;
      #pragma unroll
      for (int n = 0; n < 8; ++n) {
        float ev = emb[(k * 8 + n) * 16 + e];
        aA += wvA[n] * ev; aB += wvB[n] * ev;
      }
      q_s[rA * X_STRIDE + k * 16 + e] = aA * invA;
      q_s[rB * X_STRIDE + k * 16 + e] = aB * invB;
    }
  }
  __syncthreads();

  // ---- copyout quantized (coalesced) + loss partial ----
  #pragma unroll
  for (int it = 0; it < 2; ++it) {
    int idx = it * 256 + t;
    int rl = idx >> 6, c = idx & 63;
    int row = (rl < 4) ? (g0 + rl) : (g0 + rl - 4 + NROWS_HALF);
    out[row * 64 + c] = q_s[rl * X_STRIDE + c];
  }
  if (t == 0) atomicAdd(loss_acc, kl_s);
}

__global__ void finalize_kernel(const float* __restrict__ loss_acc, float* __restrict__ out) {
  if (threadIdx.x == 0 && blockIdx.x == 0) out[LOSS_OFF] = loss_acc[0] * 0.2f;
}

extern "C" void kernel_launch(void* const* d_in, const int* in_sizes, int n_in,
                              void* d_out, int out_size, void* d_ws, size_t ws_size,
                              hipStream_t stream) {
  const float* inp  = (const float*)d_in[0];   // [32,2048,64]
  const float* lw   = (const float*)d_in[1];   // [64,3]
  const float* lb   = (const float*)d_in[2];   // [64]
  const float* emb  = (const float*)d_in[3];   // [32,16] normalized
  const float* lws  = (const float*)d_in[4];   // [4,16,64]
  float* out = (float*)d_out;
  ushort* wsu = (ushort*)d_ws;
  float* loss = (float*)((char*)d_ws + WS_LOSS_BYTE);

  // JAX PRNG keys: key(42) -> [0,42]; split = threefry over iota(4)
  uint32_t a0, b0, a1, b1;
  tf2x32(0u, 42u, 0u, 2u, a0, b0);
  tf2x32(0u, 42u, 1u, 3u, a1, b1);
  const uint32_t kc0 = a0, kc1 = a1;   // coord-noise key
  const uint32_t kp0 = b0, kp1 = b1;   // codebook-noise key

  setup_kernel<<<509, 256, 0, stream>>>(lw, lb, wsu);
  fused_kernel<<<8192, 256, 0, stream>>>(inp, emb, lws, wsu, out, loss,
                                         kc0, kc1, kp0, kp1);
  finalize_kernel<<<1, 64, 0, stream>>>(loss, out);
}

// Round 5
// 390.285 us; speedup vs baseline: 1.6211x; 1.6211x over previous
//
#include <hip/hip_runtime.h>
#include <cstdint>

#define NROWS_HALF 32768
#define NPTS 1000
#define QC_OFF 4194304            // quantized_coord offset in d_out (floats)
#define LOSS_OFF 8388608          // loss offset in d_out (floats)

// ws layout in ushort units (bf16 stored as raw ushort):
//   [0,64512)        Vh_nd [1008][64]   (RN hi; rows 1000..1007 zero)
//   [64512,129024)   Vl_nd [1008][64]   (RN lo residual)
//   [129024,194560)  VhT   [64][1024]   (RN hi; cols 1000..1023 zero)
//   byte 520192: fp32 loss accumulator
#define U_VH_ND 0
#define U_VL_ND 64512
#define U_VHT   129024
#define WS_LOSS_BYTE 520192

#define X_STRIDE 68
#define WSTRIDE 1028              // ushort stride for W_s rows
#define MT_STRIDE 33

typedef short short8 __attribute__((ext_vector_type(8)));
typedef float float4v __attribute__((ext_vector_type(4)));

#define MFMA16(a, b, c) __builtin_amdgcn_mfma_f32_16x16x32_bf16((a), (b), (c), 0, 0, 0)

// ---------------- Threefry-2x32 (20 rounds), matches JAX ----------------
__host__ __device__ __forceinline__ void tf2x32(uint32_t k0, uint32_t k1,
                                                uint32_t x0, uint32_t x1,
                                                uint32_t& o0, uint32_t& o1) {
  const uint32_t k2 = k0 ^ k1 ^ 0x1BD11BDAu;
#define TF_R(r) { x0 += x1; x1 = (x1 << (r)) | (x1 >> (32 - (r))); x1 ^= x0; }
  x0 += k0; x1 += k1;
  TF_R(13) TF_R(15) TF_R(26) TF_R(6)
  x0 += k1; x1 += k2 + 1u;
  TF_R(17) TF_R(29) TF_R(16) TF_R(24)
  x0 += k2; x1 += k0 + 2u;
  TF_R(13) TF_R(15) TF_R(26) TF_R(6)
  x0 += k0; x1 += k1 + 3u;
  TF_R(17) TF_R(29) TF_R(16) TF_R(24)
  x0 += k1; x1 += k2 + 4u;
  TF_R(13) TF_R(15) TF_R(26) TF_R(6)
  x0 += k2; x1 += k0 + 5u;
#undef TF_R
  o0 = x0; o1 = x1;
}

// gumbel(bits) = -log(-log(u + 1e-20) + 1e-20), u = (bits>>9 | 1.0f) - 1.0f
__device__ __forceinline__ float gumbel_from_bits(uint32_t bits) {
  const uint32_t mant = bits >> 9;
  const float u = __uint_as_float(mant | 0x3f800000u) - 1.0f;
  const float delta = (float)(8388608u - mant) * 1.1920928955078125e-7f;
  float l;
  if (delta < 0.00390625f) {
    l = -(delta + 0.5f * delta * delta + 0.33333333f * delta * delta * delta);
  } else {
    l = __logf(u + 1e-20f);
  }
  return -__logf(-l + 1e-20f);
}

// round-to-nearest-even bf16 (returns 16-bit pattern in low bits)
__device__ __forceinline__ uint32_t rn16(float f) {
  uint32_t u = __float_as_uint(f);
  return (u + 0x7FFFu + ((u >> 16) & 1u)) >> 16;
}

__device__ __forceinline__ void split2_rn(float f0, float f1, uint32_t& hi, uint32_t& lo) {
  uint32_t h0 = rn16(f0), h1 = rn16(f1);
  hi = h0 | (h1 << 16);
  float l0 = f0 - __uint_as_float(h0 << 16);
  float l1 = f1 - __uint_as_float(h1 << 16);
  lo = rn16(l0) | (rn16(l1) << 16);
}

__device__ __forceinline__ void split8_rn(const float* p, short8& hi, short8& lo) {
  float4 f0 = *(const float4*)p;
  float4 f1 = *(const float4*)(p + 4);
  union { uint32_t u[4]; short8 s; } H, L;
  split2_rn(f0.x, f0.y, H.u[0], L.u[0]);
  split2_rn(f0.z, f0.w, H.u[1], L.u[1]);
  split2_rn(f1.x, f1.y, H.u[2], L.u[2]);
  split2_rn(f1.z, f1.w, H.u[3], L.u[3]);
  hi = H.s; lo = L.s;
}

__device__ __forceinline__ short8 as_s8(uint4 v) {
  union { uint4 u; short8 s; } c; c.u = v; return c.s;
}

__device__ __forceinline__ float grid_vec(int n, int c, const float* __restrict__ lw,
                                          const float* __restrict__ lb) {
  int jx = (n / 10) % 10, iy = n / 100, kz = n % 10;
  const double step = 1.5 / 9.0;
  float gx = (float)(jx * step), gy = (float)(iy * step), gz = (float)(kz * step);
  return gx * lw[c * 3 + 0] + gy * lw[c * 3 + 1] + gz * lw[c * 3 + 2] + lb[c];
}

// ---------------- setup: RN bf16 split V in both layouts, loss=0 ----------------
__global__ void setup_kernel(const float* __restrict__ lw, const float* __restrict__ lb,
                             ushort* __restrict__ wsu) {
  int idx = blockIdx.x * 256 + threadIdx.x;
  if (idx < 64512) {
    int n = idx >> 6, c = idx & 63;
    float v = (n < NPTS) ? grid_vec(n, c, lw, lb) : 0.f;
    uint32_t h = rn16(v);
    float fl = v - __uint_as_float(h << 16);
    wsu[U_VH_ND + idx] = (ushort)h;
    wsu[U_VL_ND + idx] = (ushort)rn16(fl);
  } else if (idx < 130048) {
    int i2 = idx - 64512;              // d*1024 + n
    int d = i2 >> 10, n = i2 & 1023;
    float v = (n < NPTS) ? grid_vec(n, d, lw, lb) : 0.f;
    wsu[U_VHT + i2] = (ushort)rn16(v);
  } else if (idx == 130048) {
    *(float*)((char*)wsu + WS_LOSS_BYTE) = 0.f;
  }
}

// ---------------- fused main kernel: 4096 blocks x 256 ----------------
// Block handles 16 local rows: lr 0..7 -> g0+lr, lr 8..15 -> g0+lr-8+32768 (threefry pairs)
__global__ __launch_bounds__(256, 4) void fused_kernel(
    const float* __restrict__ inp, const float* __restrict__ emb,
    const float* __restrict__ lws, const ushort* __restrict__ wsu,
    float* __restrict__ out, float* __restrict__ loss_acc,
    uint32_t kc0, uint32_t kc1, uint32_t kp0, uint32_t kp1) {

  __shared__ float x_s[16 * X_STRIDE];    // input rows; later q output
  __shared__ ushort W_s[16 * WSTRIDE];    // bf16 weights; later aliased as MT (fp32)
  __shared__ float xp_s[16 * 32];         // codebook logits
  __shared__ float red_s[128];
  __shared__ float m_s[16];
  __shared__ float invW_s[16];
  __shared__ float kl_s;

  const int t = threadIdx.x;
  const int lane = t & 63;
  const int w = t >> 6;
  const int q = lane >> 4;
  const int mn = lane & 15;
  const int g0 = blockIdx.x * 8;

  if (t == 0) kl_s = 0.f;

  // ---- load 16 input rows ----
  #pragma unroll
  for (int it = 0; it < 4; ++it) {
    int idx = it * 256 + t;
    int rl = idx >> 6, d = idx & 63;
    int row = (rl < 8) ? (g0 + rl) : (g0 + rl - 8 + NROWS_HALF);
    x_s[rl * X_STRIDE + d] = inp[row * 64 + d];
  }
  __syncthreads();

  // ---- GEMM1 (MFMA): L[i] = C-frags of X[16][64] . Vt[64][1008], split RN-bf16 ----
  // lane (q,mn) holds rows q*4+r, cols (w+4i)*16+mn. Cols >= 1000 masked to sentinel.
  float4v L[16];
  {
    short8 ah[2], al[2];
    #pragma unroll
    for (int s = 0; s < 2; ++s)
      split8_rn(&x_s[mn * X_STRIDE + s * 32 + q * 8], ah[s], al[s]);
    const ushort* Vh = wsu + U_VH_ND;
    const ushort* Vl = wsu + U_VL_ND;
    #pragma unroll
    for (int i = 0; i < 16; ++i) {
      int j = w + 4 * i;
      if (j < 63) {
        const int nb = (j * 16 + mn) * 64 + q * 8;
        uint4 bh0 = *(const uint4*)(Vh + nb);
        uint4 bl0 = *(const uint4*)(Vl + nb);
        uint4 bh1 = *(const uint4*)(Vh + nb + 32);
        uint4 bl1 = *(const uint4*)(Vl + nb + 32);
        float4v acc = {0.f, 0.f, 0.f, 0.f};
        acc = MFMA16(ah[0], as_s8(bh0), acc);
        acc = MFMA16(ah[0], as_s8(bl0), acc);
        acc = MFMA16(al[0], as_s8(bh0), acc);
        acc = MFMA16(ah[1], as_s8(bh1), acc);
        acc = MFMA16(ah[1], as_s8(bl1), acc);
        acc = MFMA16(al[1], as_s8(bh1), acc);
        // mask phantom cols 1000..1007 (tile j==62, mn>=8) to sentinel
        if (j == 62 && mn >= 8) {
          L[i] = (float4v){-1e30f, -1e30f, -1e30f, -1e30f};
        } else {
          L[i] = acc;
        }
      } else {
        L[i] = (float4v){-1e30f, -1e30f, -1e30f, -1e30f};
      }
    }
  }

  // ---- row max (shfl over mn, LDS combine over waves) ----
  {
    float mx[4];
    #pragma unroll
    for (int r = 0; r < 4; ++r) {
      float m = L[0][r];
      #pragma unroll
      for (int i = 1; i < 16; ++i) m = fmaxf(m, L[i][r]);
      mx[r] = m;
    }
    #pragma unroll
    for (int off = 1; off < 16; off <<= 1) {
      #pragma unroll
      for (int r = 0; r < 4; ++r) mx[r] = fmaxf(mx[r], __shfl_xor(mx[r], off));
    }
    if (mn == 0) {
      #pragma unroll
      for (int r = 0; r < 4; ++r) red_s[w * 16 + q * 4 + r] = mx[r];
    }
  }
  __syncthreads();
  if (t < 16)
    m_s[t] = fmaxf(fmaxf(red_s[t], red_s[16 + t]), fmaxf(red_s[32 + t], red_s[48 + t]));
  __syncthreads();

  float mrow[4];
  #pragma unroll
  for (int r = 0; r < 4; ++r) mrow[r] = m_s[q * 4 + r];

  // ---- KL stats ----
  {
    float s0[4] = {0.f, 0.f, 0.f, 0.f}, s1[4] = {0.f, 0.f, 0.f, 0.f};
    #pragma unroll
    for (int i = 0; i < 16; ++i) {
      #pragma unroll
      for (int r = 0; r < 4; ++r) {
        float e = __expf(L[i][r] - mrow[r]);   // sentinel -> exactly 0
        s0[r] += e; s1[r] += e * L[i][r];
      }
    }
    #pragma unroll
    for (int off = 1; off < 16; off <<= 1) {
      #pragma unroll
      for (int r = 0; r < 4; ++r) { s0[r] += __shfl_xor(s0[r], off); s1[r] += __shfl_xor(s1[r], off); }
    }
    if (mn == 0) {
      #pragma unroll
      for (int r = 0; r < 4; ++r) {
        red_s[w * 16 + q * 4 + r] = s0[r];
        red_s[64 + w * 16 + q * 4 + r] = s1[r];
      }
    }
  }
  __syncthreads();
  if (t < 16) {
    float S0 = (red_s[t] + red_s[16 + t]) + (red_s[32 + t] + red_s[48 + t]);
    float S1 = (red_s[64 + t] + red_s[80 + t]) + (red_s[96 + t] + red_s[112 + t]);
    atomicAdd(&kl_s, S1 / S0 - (m_s[t] + __logf(S0)) + 6.9077552790f);
  }
  __syncthreads();   // red_s free for reuse

  // ---- gumbel + weights (threefry-paired via shfl_xor 32), bf16 -> W_s ----
  {
    float mh[4], sw[4] = {0.f, 0.f, 0.f, 0.f};
    #pragma unroll
    for (int r = 0; r < 4; ++r) mh[r] = 0.5f * mrow[r];
    const int rbase = (q & 1) * 4;          // rowA local base: q0,q2 -> 0..3; q1,q3 -> 4..7
    const bool low = (q < 2);
    #pragma unroll
    for (int i = 0; i < 8; ++i) {
      const int colA = (w + 4 * i) * 16 + mn;
      const int colB = (w + 4 * (i + 8)) * 16 + mn;
      #pragma unroll
      for (int r = 0; r < 4; ++r) {
        const uint32_t rowAg = (uint32_t)(g0 + rbase + r);
        const uint32_t nown = low ? (uint32_t)colA : (uint32_t)colB;
        uint32_t y0, y1;
        uint32_t j0 = rowAg * 1000u + nown;
        tf2x32(kc0, kc1, j0, j0 + 32768000u, y0, y1);
        uint32_t send = low ? y1 : y0;
        uint32_t recv = (uint32_t)__shfl_xor((int)send, 32);
        uint32_t bA = low ? y0 : recv;      // noise for (own row, colA)
        uint32_t bB = low ? recv : y1;      // noise for (own row, colB)
        const int myrow = q * 4 + r;
        float wA = __expf((L[i][r] + gumbel_from_bits(bA)) * 0.5f - mh[r]);
        uint32_t hA = rn16(wA);
        sw[r] += __uint_as_float(hA << 16);
        W_s[myrow * WSTRIDE + (colA ^ (r * 8))] = (ushort)hA;
        float wB = __expf((L[i + 8][r] + gumbel_from_bits(bB)) * 0.5f - mh[r]);
        uint32_t hB = rn16(wB);
        sw[r] += __uint_as_float(hB << 16);
        if (colB < 1008) W_s[myrow * WSTRIDE + (colB ^ (r * 8))] = (ushort)hB;
      }
    }
    #pragma unroll
    for (int off = 1; off < 16; off <<= 1) {
      #pragma unroll
      for (int r = 0; r < 4; ++r) sw[r] += __shfl_xor(sw[r], off);
    }
    if (mn == 0) {
      #pragma unroll
      for (int r = 0; r < 4; ++r) red_s[w * 16 + q * 4 + r] = sw[r];
    }
  }
  // zero LOGICAL pad cols 1008..1023 through the per-row XOR map (disjoint from
  // weight writes: logical sets disjoint -> physical sets disjoint)
  {
    int rowp = t >> 4;
    int cp = 1008 + (t & 15);
    W_s[rowp * WSTRIDE + (cp ^ ((rowp & 3) * 8))] = 0;
  }
  __syncthreads();
  if (t < 16)
    invW_s[t] = 1.f / ((red_s[t] + red_s[16 + t]) + (red_s[32 + t] + red_s[48 + t]));
  __syncthreads();

  // ---- GEMM2 (MFMA): qc[16][64] = W[16][1024] . VhT^T; wave w -> d-tile w ----
  {
    const ushort* VhT = wsu + U_VHT;
    const int dq = w * 16 + mn;
    const int swz = (mn & 3) * 8;
    float4v acc = {0.f, 0.f, 0.f, 0.f};
    for (int s = 0; s < 32; ++s) {
      uint4 aw = *(const uint4*)(W_s + mn * WSTRIDE + ((s * 32 + q * 8) ^ swz));
      uint4 bh = *(const uint4*)(VhT + dq * 1024 + s * 32 + q * 8);
      acc = MFMA16(as_s8(aw), as_s8(bh), acc);
    }
    #pragma unroll
    for (int r = 0; r < 4; ++r) {
      int m = q * 4 + r;
      int grow = (m < 8) ? (g0 + m) : (g0 + m - 8 + NROWS_HALF);
      out[QC_OFF + grow * 64 + dq] = acc[r] * invW_s[m];
    }
  }
  __syncthreads();   // W_s free -> alias MT

  // ---- MT[64][33] (d-major): MT[d][m] = sum_e embK[k,n,e]*lin_ws[k,e,d] ----
  float* MT = (float*)W_s;
  #pragma unroll
  for (int e = 0; e < 8; ++e) {
    int idx = e * 256 + t;     // 2048 entries: mm = idx>>6, d = idx&63
    int mm = idx >> 6, d = idx & 63, k = mm >> 3;
    float a = 0.f;
    #pragma unroll
    for (int ee = 0; ee < 16; ++ee) a += emb[mm * 16 + ee] * lws[(k * 16 + ee) * 64 + d];
    MT[d * MT_STRIDE + mm] = a;
  }
  __syncthreads();

  // ---- phase 5a: xp = x . M^T (thread: rows t>>5 and +8, m32 = t&31) ----
  {
    const int rl = t >> 5, m32 = t & 31;
    float a0 = 0.f, a1 = 0.f;
    #pragma unroll
    for (int d = 0; d < 64; ++d) {
      float mv = MT[d * MT_STRIDE + m32];
      a0 = fmaf(x_s[rl * X_STRIDE + d], mv, a0);
      a1 = fmaf(x_s[(rl + 8) * X_STRIDE + d], mv, a1);
    }
    xp_s[rl * 32 + m32] = a0;
    xp_s[(rl + 8) * 32 + m32] = a1;
  }
  __syncthreads();

  // ---- phase 5b: per (pair p, k): KL_p, gumbel-softmax, q = ip . embK ----
  float* q_s = x_s;   // x dead after 5a
  if (t < 32) {
    const int p = t >> 2, k = t & 3;
    const int rA = p, rB = p + 8;
    float xpA[8], xpB[8];
    #pragma unroll
    for (int n = 0; n < 8; ++n) {
      xpA[n] = xp_s[rA * 32 + k * 8 + n];
      xpB[n] = xp_s[rB * 32 + k * 8 + n];
    }
    float mA = xpA[0], mB = xpB[0];
    #pragma unroll
    for (int n = 1; n < 8; ++n) { mA = fmaxf(mA, xpA[n]); mB = fmaxf(mB, xpB[n]); }
    float s0A = 0.f, s1A = 0.f, s0B = 0.f, s1B = 0.f;
    #pragma unroll
    for (int n = 0; n < 8; ++n) {
      float eA = __expf(xpA[n] - mA); s0A += eA; s1A += eA * xpA[n];
      float eB = __expf(xpB[n] - mB); s0B += eB; s1B += eB * xpB[n];
    }
    atomicAdd(&kl_s, (s1A / s0A - (mA + __logf(s0A)) + 2.0794415417f) +
                     (s1B / s0B - (mB + __logf(s0B)) + 2.0794415417f));
    uint32_t base = (uint32_t)(g0 + p) * 32u + (uint32_t)k * 8u;
    float tA[8], tB[8], m2A = -3.0e38f, m2B = -3.0e38f;
    #pragma unroll
    for (int n = 0; n < 8; ++n) {
      uint32_t y0, y1;
      tf2x32(kp0, kp1, base + n, base + n + 1048576u, y0, y1);
      tA[n] = (xpA[n] + gumbel_from_bits(y0)) * 0.5f;
      tB[n] = (xpB[n] + gumbel_from_bits(y1)) * 0.5f;
      m2A = fmaxf(m2A, tA[n]); m2B = fmaxf(m2B, tB[n]);
    }
    float wvA[8], wvB[8], swA = 0.f, swB = 0.f;
    #pragma unroll
    for (int n = 0; n < 8; ++n) {
      wvA[n] = __expf(tA[n] - m2A); swA += wvA[n];
      wvB[n] = __expf(tB[n] - m2B); swB += wvB[n];
    }
    float invA = 1.0f / swA, invB = 1.0f / swB;
    #pragma unroll
    for (int e = 0; e < 16; ++e) {
      float aA = 0.f, aB = 0.f;
      #pragma unroll
      for (int n = 0; n < 8; ++n) {
        float ev = emb[(k * 8 + n) * 16 + e];
        aA += wvA[n] * ev; aB += wvB[n] * ev;
      }
      q_s[rA * X_STRIDE + k * 16 + e] = aA * invA;
      q_s[rB * X_STRIDE + k * 16 + e] = aB * invB;
    }
  }
  __syncthreads();

  // ---- copyout quantized (coalesced) + loss partial ----
  #pragma unroll
  for (int it = 0; it < 4; ++it) {
    int idx = it * 256 + t;
    int rl = idx >> 6, c = idx & 63;
    int row = (rl < 8) ? (g0 + rl) : (g0 + rl - 8 + NROWS_HALF);
    out[row * 64 + c] = q_s[rl * X_STRIDE + c];
  }
  if (t == 0) atomicAdd(loss_acc, kl_s);
}

__global__ void finalize_kernel(const float* __restrict__ loss_acc, float* __restrict__ out) {
  if (threadIdx.x == 0 && blockIdx.x == 0) out[LOSS_OFF] = loss_acc[0] * 0.2f;
}

extern "C" void kernel_launch(void* const* d_in, const int* in_sizes, int n_in,
                              void* d_out, int out_size, void* d_ws, size_t ws_size,
                              hipStream_t stream) {
  const float* inp  = (const float*)d_in[0];   // [32,2048,64]
  const float* lw   = (const float*)d_in[1];   // [64,3]
  const float* lb   = (const float*)d_in[2];   // [64]
  const float* emb  = (const float*)d_in[3];   // [32,16] normalized
  const float* lws  = (const float*)d_in[4];   // [4,16,64]
  float* out = (float*)d_out;
  ushort* wsu = (ushort*)d_ws;
  float* loss = (float*)((char*)d_ws + WS_LOSS_BYTE);

  // JAX PRNG keys: key(42) -> [0,42]; split = threefry over iota(4)
  uint32_t a0, b0, a1, b1;
  tf2x32(0u, 42u, 0u, 2u, a0, b0);
  tf2x32(0u, 42u, 1u, 3u, a1, b1);
  const uint32_t kc0 = a0, kc1 = a1;   // coord-noise key
  const uint32_t kp0 = b0, kp1 = b1;   // codebook-noise key

  setup_kernel<<<509, 256, 0, stream>>>(lw, lb, wsu);
  fused_kernel<<<4096, 256, 0, stream>>>(inp, emb, lws, wsu, out, loss,
                                         kc0, kc1, kp0, kp1);
  finalize_kernel<<<1, 64, 0, stream>>>(loss, out);
}

// Round 7
// 348.751 us; speedup vs baseline: 1.8142x; 1.1191x over previous
//
#include <hip/hip_runtime.h>
#include <cstdint>

#define NROWS_HALF 32768
#define NPTS 1000
#define QC_OFF 4194304            // quantized_coord offset in d_out (floats)
#define LOSS_OFF 8388608          // loss offset in d_out (floats)

// ws layout in ushort units (bf16 stored as raw ushort):
//   U_VH  [1040][64]: rows 0..999 coord vecs (RN hi), 1000..1007 zero,
//                     rows 1008..1039 = M codes (m = row-1008)
//   U_VL  [1040][64]: matching RN lo residuals
//   U_VHT [64][1024]: d-major coord vecs (RN hi; cols 1000..1023 zero)
//   byte 397312: fp32 loss accumulator
#define U_VH 0
#define U_VL 66560
#define U_VHT 133120
#define WS_LOSS_BYTE 397312

#define X_STRIDE 68
#define WSTRIDE 1028              // ushort stride for W_s rows (2-way-max banks)

typedef short short8 __attribute__((ext_vector_type(8)));
typedef float float4v __attribute__((ext_vector_type(4)));

#define MFMA16(a, b, c) __builtin_amdgcn_mfma_f32_16x16x32_bf16((a), (b), (c), 0, 0, 0)

// ---------------- Threefry-2x32 (20 rounds), matches JAX ----------------
__host__ __device__ __forceinline__ void tf2x32(uint32_t k0, uint32_t k1,
                                                uint32_t x0, uint32_t x1,
                                                uint32_t& o0, uint32_t& o1) {
  const uint32_t k2 = k0 ^ k1 ^ 0x1BD11BDAu;
#define TF_R(r) { x0 += x1; x1 = (x1 << (r)) | (x1 >> (32 - (r))); x1 ^= x0; }
  x0 += k0; x1 += k1;
  TF_R(13) TF_R(15) TF_R(26) TF_R(6)
  x0 += k1; x1 += k2 + 1u;
  TF_R(17) TF_R(29) TF_R(16) TF_R(24)
  x0 += k2; x1 += k0 + 2u;
  TF_R(13) TF_R(15) TF_R(26) TF_R(6)
  x0 += k0; x1 += k1 + 3u;
  TF_R(17) TF_R(29) TF_R(16) TF_R(24)
  x0 += k1; x1 += k2 + 4u;
  TF_R(13) TF_R(15) TF_R(26) TF_R(6)
  x0 += k2; x1 += k0 + 5u;
#undef TF_R
  o0 = x0; o1 = x1;
}

// gumbel(bits) = -log(-log(u + 1e-20) + 1e-20), u = (bits>>9 | 1.0f) - 1.0f
__device__ __forceinline__ float gumbel_from_bits(uint32_t bits) {
  const uint32_t mant = bits >> 9;
  const float u = __uint_as_float(mant | 0x3f800000u) - 1.0f;
  const float delta = (float)(8388608u - mant) * 1.1920928955078125e-7f;
  float l;
  if (delta < 0.00390625f) {
    l = -(delta + 0.5f * delta * delta + 0.33333333f * delta * delta * delta);
  } else {
    l = __logf(u + 1e-20f);
  }
  return -__logf(-l + 1e-20f);
}

// round-to-nearest-even bf16 (returns 16-bit pattern in low bits)
__device__ __forceinline__ uint32_t rn16(float f) {
  uint32_t u = __float_as_uint(f);
  return (u + 0x7FFFu + ((u >> 16) & 1u)) >> 16;
}

__device__ __forceinline__ void split2_rn(float f0, float f1, uint32_t& hi, uint32_t& lo) {
  uint32_t h0 = rn16(f0), h1 = rn16(f1);
  hi = h0 | (h1 << 16);
  float l0 = f0 - __uint_as_float(h0 << 16);
  float l1 = f1 - __uint_as_float(h1 << 16);
  lo = rn16(l0) | (rn16(l1) << 16);
}

__device__ __forceinline__ void split8_rn(const float* p, short8& hi, short8& lo) {
  float4 f0 = *(const float4*)p;
  float4 f1 = *(const float4*)(p + 4);
  union { uint32_t u[4]; short8 s; } H, L;
  split2_rn(f0.x, f0.y, H.u[0], L.u[0]);
  split2_rn(f0.z, f0.w, H.u[1], L.u[1]);
  split2_rn(f1.x, f1.y, H.u[2], L.u[2]);
  split2_rn(f1.z, f1.w, H.u[3], L.u[3]);
  hi = H.s; lo = L.s;
}

__device__ __forceinline__ short8 as_s8(uint4 v) {
  union { uint4 u; short8 s; } c; c.u = v; return c.s;
}

__device__ __forceinline__ float grid_vec(int n, int c, const float* __restrict__ lw,
                                          const float* __restrict__ lb) {
  int jx = (n / 10) % 10, iy = n / 100, kz = n % 10;
  const double step = 1.5 / 9.0;
  float gx = (float)(jx * step), gy = (float)(iy * step), gz = (float)(kz * step);
  return gx * lw[c * 3 + 0] + gy * lw[c * 3 + 1] + gz * lw[c * 3 + 2] + lb[c];
}

// one 16-col tile of GEMM1: 3-MFMA split-bf16 (hi+lo), B rows nb..nb+15
__device__ __forceinline__ float4v tile_mfma(const ushort* __restrict__ Vh,
                                             const ushort* __restrict__ Vl,
                                             int nb, const short8* ah, const short8* al) {
  uint4 bh0 = *(const uint4*)(Vh + nb);
  uint4 bl0 = *(const uint4*)(Vl + nb);
  uint4 bh1 = *(const uint4*)(Vh + nb + 32);
  uint4 bl1 = *(const uint4*)(Vl + nb + 32);
  float4v acc = {0.f, 0.f, 0.f, 0.f};
  acc = MFMA16(ah[0], as_s8(bh0), acc);
  acc = MFMA16(ah[0], as_s8(bl0), acc);
  acc = MFMA16(al[0], as_s8(bh0), acc);
  acc = MFMA16(ah[1], as_s8(bh1), acc);
  acc = MFMA16(ah[1], as_s8(bl1), acc);
  acc = MFMA16(al[1], as_s8(bh1), acc);
  return acc;
}

// ---------------- setup: V tables + M codes + loss=0 ----------------
__global__ void setup_kernel(const float* __restrict__ lw, const float* __restrict__ lb,
                             const float* __restrict__ emb, const float* __restrict__ lws,
                             ushort* __restrict__ wsu) {
  int idx = blockIdx.x * 256 + threadIdx.x;
  if (idx < 66560) {
    int n = idx >> 6, c = idx & 63;
    float v;
    if (n < NPTS) {
      v = grid_vec(n, c, lw, lb);
    } else if (n < 1008) {
      v = 0.f;
    } else {
      int m = n - 1008, k = m >> 3;
      float a = 0.f;
      #pragma unroll
      for (int e = 0; e < 16; ++e) a += emb[m * 16 + e] * lws[(k * 16 + e) * 64 + c];
      v = a;
    }
    uint32_t h = rn16(v);
    float fl = v - __uint_as_float(h << 16);
    wsu[U_VH + idx] = (ushort)h;
    wsu[U_VL + idx] = (ushort)rn16(fl);
  } else if (idx < 132096) {
    int i2 = idx - 66560;              // d*1024 + n
    int d = i2 >> 10, n = i2 & 1023;
    float v = (n < NPTS) ? grid_vec(n, d, lw, lb) : 0.f;
    wsu[U_VHT + i2] = (ushort)rn16(v);
  } else if (idx == 132096) {
    *(float*)((char*)wsu + WS_LOSS_BYTE) = 0.f;
  }
}

// ---------------- fused main kernel: 4096 blocks x 256 ----------------
// Block: 16 local rows; lr 0..7 -> g0+lr, lr 8..15 -> g0+lr-8+32768 (threefry pairs)
__global__ __launch_bounds__(256, 4) void fused_kernel(
    const float* __restrict__ inp, const float* __restrict__ emb,
    const float* __restrict__ lw, const float* __restrict__ lb,
    const ushort* __restrict__ wsu, float* __restrict__ out,
    float* __restrict__ loss_acc,
    uint32_t kc0, uint32_t kc1, uint32_t kp0, uint32_t kp1) {

  __shared__ float x_s[16 * X_STRIDE];    // input rows; later q output
  __shared__ ushort W_s[16 * WSTRIDE];    // bf16 gumbel weights
  __shared__ float xp_s[16 * 32];         // codebook logits
  __shared__ float red_s[192];            // [0,64) s0, [64,128) s1, [128,192) sw
  __shared__ float max_s[16];             // exact per-row logit max
  __shared__ float kl_s;

  const int t = threadIdx.x;
  const int lane = t & 63;
  const int w = t >> 6;
  const int q = lane >> 4;
  const int mn = lane & 15;
  const int g0 = blockIdx.x * 8;

  if (t == 0) kl_s = 0.f;

  // per-lane projection coefficients (lane = channel c)
  const float pw0 = lw[lane * 3 + 0];
  const float pw1 = lw[lane * 3 + 1];
  const float pw2 = lw[lane * 3 + 2];
  const float pbb = lb[lane];

  // ---- load 16 input rows + EXACT per-row logit max ----
  // logits over grid: u.g + beta, g in corners-included grid =>
  // max = 1.5*(relu(u0)+relu(u1)+relu(u2)) + beta, u = W^T x, beta = x.b
  #pragma unroll
  for (int it = 0; it < 4; ++it) {
    int rl = it * 4 + w;
    int row = (rl < 8) ? (g0 + rl) : (g0 + rl - 8 + NROWS_HALF);
    float v = inp[row * 64 + lane];
    x_s[rl * X_STRIDE + lane] = v;
    float u0 = v * pw0, u1 = v * pw1, u2 = v * pw2, u3 = v * pbb;
    #pragma unroll
    for (int off = 32; off > 0; off >>= 1) {
      u0 += __shfl_xor(u0, off);
      u1 += __shfl_xor(u1, off);
      u2 += __shfl_xor(u2, off);
      u3 += __shfl_xor(u3, off);
    }
    if (lane == 0)
      max_s[rl] = 1.5f * (fmaxf(u0, 0.f) + fmaxf(u1, 0.f) + fmaxf(u2, 0.f)) + u3;
  }
  __syncthreads();

  // ---- A fragments (rows = local rows, m = mn) ----
  short8 ah[2], al[2];
  #pragma unroll
  for (int s = 0; s < 2; ++s)
    split8_rn(&x_s[mn * X_STRIDE + s * 32 + q * 8], ah[s], al[s]);

  float mrow[4], mh[4];
  #pragma unroll
  for (int r = 0; r < 4; ++r) { mrow[r] = max_s[q * 4 + r]; mh[r] = 0.5f * mrow[r]; }

  const ushort* Vh = wsu + U_VH;
  const ushort* Vl = wsu + U_VL;
  const int rbase = (q & 1) * 4;
  const bool low = (q < 2);

  float s0[4] = {0.f, 0.f, 0.f, 0.f};
  float s1[4] = {0.f, 0.f, 0.f, 0.f};
  float sw[4] = {0.f, 0.f, 0.f, 0.f};

  // ---- streaming GEMM1 + KL stats + gumbel weights, tile-pairs (i, i+8) ----
  #pragma unroll 2
  for (int i = 0; i < 8; ++i) {
    const int jA = w + 4 * i, jB = jA + 32;
    float4v accA = tile_mfma(Vh, Vl, (jA * 16 + mn) * 64 + q * 8, ah, al);
    float4v accB;
    if (jB < 63) {
      accB = tile_mfma(Vh, Vl, (jB * 16 + mn) * 64 + q * 8, ah, al);
      if (jB == 62 && mn >= 8) accB = (float4v){-1e30f, -1e30f, -1e30f, -1e30f};
    } else {
      accB = (float4v){-1e30f, -1e30f, -1e30f, -1e30f};
    }
    // KL stats with exact-max shift
    #pragma unroll
    for (int r = 0; r < 4; ++r) {
      float eA = __expf(accA[r] - mrow[r]); s0[r] += eA; s1[r] += eA * accA[r];
      float eB = __expf(accB[r] - mrow[r]); s0[r] += eB; s1[r] += eB * accB[r];
    }
    // gumbel noise (threefry-paired via shfl_xor 32) + bf16 weights -> W_s
    const int colA = jA * 16 + mn, colB = jB * 16 + mn;
    #pragma unroll
    for (int r = 0; r < 4; ++r) {
      const uint32_t rowAg = (uint32_t)(g0 + rbase + r);
      const uint32_t nown = low ? (uint32_t)colA : (uint32_t)colB;
      uint32_t y0, y1;
      uint32_t j0 = rowAg * 1000u + nown;
      tf2x32(kc0, kc1, j0, j0 + 32768000u, y0, y1);
      uint32_t send = low ? y1 : y0;
      uint32_t recv = (uint32_t)__shfl_xor((int)send, 32);
      uint32_t bA = low ? y0 : recv;
      uint32_t bB = low ? recv : y1;
      const int myrow = q * 4 + r;
      float wA = __expf((accA[r] + gumbel_from_bits(bA)) * 0.5f - mh[r]);
      uint32_t hA = rn16(wA);
      sw[r] += __uint_as_float(hA << 16);
      W_s[myrow * WSTRIDE + (colA ^ (r * 8))] = (ushort)hA;
      float wB = __expf((accB[r] + gumbel_from_bits(bB)) * 0.5f - mh[r]);
      uint32_t hB = rn16(wB);
      sw[r] += __uint_as_float(hB << 16);
      if (colB < 1008) W_s[myrow * WSTRIDE + (colB ^ (r * 8))] = (ushort)hB;
    }
  }

  // ---- reduce stats over mn within quad; stash wave-partials ----
  #pragma unroll
  for (int off = 1; off < 16; off <<= 1) {
    #pragma unroll
    for (int r = 0; r < 4; ++r) {
      s0[r] += __shfl_xor(s0[r], off);
      s1[r] += __shfl_xor(s1[r], off);
      sw[r] += __shfl_xor(sw[r], off);
    }
  }
  if (mn == 0) {
    #pragma unroll
    for (int r = 0; r < 4; ++r) {
      red_s[w * 16 + q * 4 + r] = s0[r];
      red_s[64 + w * 16 + q * 4 + r] = s1[r];
      red_s[128 + w * 16 + q * 4 + r] = sw[r];
    }
  }

  // ---- code tiles: xp logits via same A-frags (M rows 1008..1039) ----
  if (w == 0 || w == 3) {
    const int ct = (w == 0) ? 64 : 63;
    float4v acc = tile_mfma(Vh, Vl, (ct * 16 + mn) * 64 + q * 8, ah, al);
    #pragma unroll
    for (int r = 0; r < 4; ++r)
      xp_s[(q * 4 + r) * 32 + (ct - 63) * 16 + mn] = acc[r];
  }

  // ---- zero LOGICAL pad cols 1008..1023 through the per-row XOR map ----
  {
    int rowp = t >> 4;
    int cp = 1008 + (t & 15);
    W_s[rowp * WSTRIDE + (cp ^ ((rowp & 3) * 8))] = 0;
  }
  __syncthreads();

  // ---- KL finalize (t<16) ----
  if (t < 16) {
    float S0 = (red_s[t] + red_s[16 + t]) + (red_s[32 + t] + red_s[48 + t]);
    float S1 = (red_s[64 + t] + red_s[80 + t]) + (red_s[96 + t] + red_s[112 + t]);
    atomicAdd(&kl_s, S1 / S0 - (max_s[t] + __logf(S0)) + 6.9077552790f);
  }

  // ---- GEMM2 (MFMA): qc[16][64] = W[16][1024] . V; wave w -> d-tile w ----
  {
    const ushort* VhT = wsu + U_VHT;
    const int dq = w * 16 + mn;
    const int swz = (mn & 3) * 8;
    float4v acc = {0.f, 0.f, 0.f, 0.f};
    for (int s = 0; s < 32; ++s) {
      uint4 aw = *(const uint4*)(W_s + mn * WSTRIDE + ((s * 32 + q * 8) ^ swz));
      uint4 bh = *(const uint4*)(VhT + dq * 1024 + s * 32 + q * 8);
      acc = MFMA16(as_s8(aw), as_s8(bh), acc);
    }
    #pragma unroll
    for (int r = 0; r < 4; ++r) {
      int m = q * 4 + r;
      float sww = (red_s[128 + m] + red_s[144 + m]) + (red_s[160 + m] + red_s[176 + m]);
      int grow = (m < 8) ? (g0 + m) : (g0 + m - 8 + NROWS_HALF);
      out[QC_OFF + grow * 64 + dq] = acc[r] / sww;
    }
  }

  // ---- 5b: per (pair p, k) codebook path; 8 lanes per wave (32 units) ----
  float* q_s = x_s;   // x dead (A-frags extracted pre-loop)
  if (lane < 8) {
    const int u = w * 8 + lane;
    const int p = u >> 2, k = u & 3;
    const int rA = p, rB = p + 8;
    float xpA[8], xpB[8];
    #pragma unroll
    for (int n = 0; n < 8; ++n) {
      xpA[n] = xp_s[rA * 32 + k * 8 + n];
      xpB[n] = xp_s[rB * 32 + k * 8 + n];
    }
    float mA = xpA[0], mB = xpB[0];
    #pragma unroll
    for (int n = 1; n < 8; ++n) { mA = fmaxf(mA, xpA[n]); mB = fmaxf(mB, xpB[n]); }
    float s0A = 0.f, s1A = 0.f, s0B = 0.f, s1B = 0.f;
    #pragma unroll
    for (int n = 0; n < 8; ++n) {
      float eA = __expf(xpA[n] - mA); s0A += eA; s1A += eA * xpA[n];
      float eB = __expf(xpB[n] - mB); s0B += eB; s1B += eB * xpB[n];
    }
    atomicAdd(&kl_s, (s1A / s0A - (mA + __logf(s0A)) + 2.0794415417f) +
                     (s1B / s0B - (mB + __logf(s0B)) + 2.0794415417f));
    uint32_t base = (uint32_t)(g0 + p) * 32u + (uint32_t)k * 8u;
    float tA[8], tB[8], m2A = -3.0e38f, m2B = -3.0e38f;
    #pragma unroll
    for (int n = 0; n < 8; ++n) {
      uint32_t y0, y1;
      tf2x32(kp0, kp1, base + n, base + n + 1048576u, y0, y1);
      tA[n] = (xpA[n] + gumbel_from_bits(y0)) * 0.5f;
      tB[n] = (xpB[n] + gumbel_from_bits(y1)) * 0.5f;
      m2A = fmaxf(m2A, tA[n]); m2B = fmaxf(m2B, tB[n]);
    }
    float wvA[8], wvB[8], swA = 0.f, swB = 0.f;
    #pragma unroll
    for (int n = 0; n < 8; ++n) {
      wvA[n] = __expf(tA[n] - m2A); swA += wvA[n];
      wvB[n] = __expf(tB[n] - m2B); swB += wvB[n];
    }
    float invA = 1.0f / swA, invB = 1.0f / swB;
    #pragma unroll
    for (int e = 0; e < 16; ++e) {
      float aA = 0.f, aB = 0.f;
      #pragma unroll
      for (int n = 0; n < 8; ++n) {
        float ev = emb[(k * 8 + n) * 16 + e];
        aA += wvA[n] * ev; aB += wvB[n] * ev;
      }
      q_s[rA * X_STRIDE + k * 16 + e] = aA * invA;
      q_s[rB * X_STRIDE + k * 16 + e] = aB * invB;
    }
  }
  __syncthreads();

  // ---- copyout quantized (coalesced) + loss partial ----
  #pragma unroll
  for (int it = 0; it < 4; ++it) {
    int idx = it * 256 + t;
    int rl = idx >> 6, c = idx & 63;
    int row = (rl < 8) ? (g0 + rl) : (g0 + rl - 8 + NROWS_HALF);
    out[row * 64 + c] = q_s[rl * X_STRIDE + c];
  }
  if (t == 0) atomicAdd(loss_acc, kl_s);
}

__global__ void finalize_kernel(const float* __restrict__ loss_acc, float* __restrict__ out) {
  if (threadIdx.x == 0 && blockIdx.x == 0) out[LOSS_OFF] = loss_acc[0] * 0.2f;
}

extern "C" void kernel_launch(void* const* d_in, const int* in_sizes, int n_in,
                              void* d_out, int out_size, void* d_ws, size_t ws_size,
                              hipStream_t stream) {
  const float* inp  = (const float*)d_in[0];   // [32,2048,64]
  const float* lw   = (const float*)d_in[1];   // [64,3]
  const float* lb   = (const float*)d_in[2];   // [64]
  const float* emb  = (const float*)d_in[3];   // [32,16] normalized
  const float* lws  = (const float*)d_in[4];   // [4,16,64]
  float* out = (float*)d_out;
  ushort* wsu = (ushort*)d_ws;
  float* loss = (float*)((char*)d_ws + WS_LOSS_BYTE);

  // JAX PRNG keys: key(42) -> [0,42]; split = threefry over iota(4)
  uint32_t a0, b0, a1, b1;
  tf2x32(0u, 42u, 0u, 2u, a0, b0);
  tf2x32(0u, 42u, 1u, 3u, a1, b1);
  const uint32_t kc0 = a0, kc1 = a1;   // coord-noise key
  const uint32_t kp0 = b0, kp1 = b1;   // codebook-noise key

  setup_kernel<<<517, 256, 0, stream>>>(lw, lb, emb, lws, wsu);
  fused_kernel<<<4096, 256, 0, stream>>>(inp, emb, lw, lb, wsu, out, loss,
                                         kc0, kc1, kp0, kp1);
  finalize_kernel<<<1, 64, 0, stream>>>(loss, out);
}